// Round 23
// baseline (257.642 us; speedup 1.0000x reference)
//
#include <hip/hip_runtime.h>

#define BB 256
#define SS 16
#define II 64
#define DD 128
#define TT 65            // I + 1 (BOS prepended)
#define BOS_ID 100000
#define XROW 256         // x row stride: 128 bf16, XOR-16B swizzled (byte ^= (row&7)<<4)
#define XROWS 73         // 8 zero guard rows + 65 positions
#define XT (XROWS*XROW)  // 18688 B per tile

// ---------------- ws layout (bytes) ----------------
#define OFF_LEN  0                        // int lengths[B][S]            16384
#define OFF_ML   16384                    // int maxlen[S]                64
#define OFF_ME   32768                    // float mean_emb[B][S][D]      2 MB
#define OFF_HB   (32768 + 2097152)        // float hB[S][B][D]            2 MB
#define OFF_WB2  (OFF_HB + 2097152)       // bf16 wB2[80 half-chunks][2048]  327680
#define OFF_WIHP (OFF_WB2 + 327680)       // u32 wih4[16][384][4]         98304
#define OFF_WGRU (OFF_WIHP + 98304)       // u32 wgru4[16][512][4]        131072

// ---------------- out layout (float elements) ----------------
#define OUT_MASK  (BB*SS*TT*DD)          // 34,078,720
#define OUT_UTYPE (OUT_MASK + BB*SS*TT)

typedef __attribute__((ext_vector_type(8))) short short8;
typedef __attribute__((ext_vector_type(4))) float f32x4;

__device__ __forceinline__ unsigned short f2bf(float f) {
    unsigned int u = __builtin_bit_cast(unsigned int, f);
    return (unsigned short)((u + 0x7fffu + ((u >> 16) & 1u)) >> 16);  // RNE
}
__device__ __forceinline__ float bflo(unsigned int u) {
    return __builtin_bit_cast(float, u << 16);
}
__device__ __forceinline__ float bfhi(unsigned int u) {
    return __builtin_bit_cast(float, u & 0xffff0000u);
}
__device__ __forceinline__ void gld16(const void* g, void* l) {
    __builtin_amdgcn_global_load_lds(
        (const __attribute__((address_space(1))) void*)g,
        (__attribute__((address_space(3))) void*)l, 16, 0, 0);
}

// ============ kernel 0: weight prep + len (merged; len = blocks 864..879) ============
__global__ __launch_bounds__(256) void prep_kernel(
    const float* __restrict__ w0, const float* __restrict__ w1,
    const float* __restrict__ w2, const float* __restrict__ fus_w,
    const float* __restrict__ wih, const float* __restrict__ whh,
    const int* __restrict__ item_id, const int* __restrict__ u_type,
    unsigned short* __restrict__ wB2,
    unsigned int* __restrict__ wih4, unsigned int* __restrict__ wgru4,
    int* __restrict__ lengths, int* __restrict__ maxlen,
    float* __restrict__ u_out)
{
    if (blockIdx.x >= 864) {            // ---- len work ----
        int s = blockIdx.x - 864;
        int b = threadIdx.x;
        const int* row = item_id + (b * SS + s) * II;
        int cnt = 0;
        for (int i = 0; i < II; ++i) cnt += (row[i] > 0);
        lengths[b * SS + s] = cnt;
        __shared__ int red[256];
        red[b] = cnt;
        __syncthreads();
        for (int off = 128; off > 0; off >>= 1) {
            if (b < off) red[b] = max(red[b], red[b + off]);
            __syncthreads();
        }
        if (b == 0) maxlen[s] = red[0];
        if (s == 0) u_out[b] = (float)u_type[b];
        return;
    }
    int idx = blockIdx.x * 256 + threadIdx.x;
    if (idx < 163840) {
        int cid2  = idx >> 11;           // 0..79
        int inner = idx & 2047;
        int g = inner >> 9;
        int c = (inner >> 3) & 63;
        int e = inner & 7;
        int nh   = cid2 & 1;
        int rest = cid2 >> 1;            // 0..39
        int cq   = rest & 3;
        int m    = rest >> 2;            // 0..8 conv, 9 fusion
        int ci = cq * 32 + g * 8 + e;
        int co = nh * 64 + c;
        float v;
        if (m < 9) {
            int L = m / 3, k = m % 3;
            const float* w = (L == 0) ? w0 : ((L == 1) ? w1 : w2);
            v = w[(co * 128 + ci) * 3 + k];
            if (k == 2 && ci == co) v += 1.0f;   // fold residual into GEMM
        } else {
            v = fus_w[co * 256 + ci];    // tc half of fus_w
        }
        wB2[idx] = f2bf(v);
    } else if (idx < 163840 + 24576) {
        int f   = idx - 163840;          // [dd4][r][c]: 16 x 384 x 4
        int dd4 = f / 1536;
        int rem = f - dd4 * 1536;
        int r   = rem >> 2;
        int c   = rem & 3;
        int d0  = 8 * dd4 + 2 * c;
        unsigned int lo = f2bf(wih[r * 128 + d0]);
        unsigned int hi = f2bf(wih[r * 128 + d0 + 1]);
        wih4[f] = (hi << 16) | lo;
    } else if (idx < 163840 + 24576 + 32768) {
        int f   = idx - 163840 - 24576;  // [dd4][r][c]: 16 x 512 x 4
        int dd4 = f >> 11;
        int rem = f & 2047;
        int r   = rem >> 2;
        int c   = rem & 3;
        int d0  = 8 * dd4 + 2 * c;
        float v0, v1;
        if (r < 384) { v0 = whh[r * 128 + d0]; v1 = whh[r * 128 + d0 + 1]; }
        else { const float* fw = fus_w + (r - 384) * 256 + 128;
               v0 = fw[d0]; v1 = fw[d0 + 1]; }
        wgru4[f] = ((unsigned int)f2bf(v1) << 16) | (unsigned int)f2bf(v0);
    }
}

// ============ kernel 2: masks + mean_emb v2 (256 thr, row-parity split) ============
__global__ __launch_bounds__(256) void mean_kernel(
    const int* __restrict__ item_id, const int* __restrict__ eval_from,
    const float* __restrict__ emb,
    const int* __restrict__ lengths, const int* __restrict__ maxlen,
    float* __restrict__ mean_emb, float* __restrict__ mask_out)
{
    int bid = blockIdx.x;
    int b = bid >> 4, s = bid & 15;
    int tid = threadIdx.x;
    int d = tid & 127, tg = tid >> 7;
    __shared__ int seqs[TT];
    __shared__ int msk[TT];
    __shared__ float part[DD];
    int ml  = maxlen[s];
    int len = lengths[bid];
    int ef  = eval_from[b];
    if (tid < TT) {
        int v;
        if (tid == 0) v = BOS_ID;
        else { int it = item_id[bid * II + tid - 1]; v = it > 0 ? it : 0; }
        if (tid > ml) v = 0;
        int m = (v != 0) && !(tid == len && len > 0);
        seqs[tid] = v;
        msk[tid]  = m;
        mask_out[bid * TT + tid] = (m && (s >= ef)) ? 1.0f : 0.0f;
    }
    __syncthreads();
    int cnt = 0;
    for (int p = 0; p < TT; ++p) cnt += msk[p];
    float acc = 0.0f;
    for (int p = tg; p < TT; p += 2) {
        if (msk[p]) acc += emb[(long)seqs[p] * DD + d];
    }
    if (tg == 1) part[d] = acc;
    __syncthreads();
    if (tg == 0)
        mean_emb[bid * DD + d] = (acc + part[d]) / (float)max(cnt, 1);
}

// ============ kernel 3: FUSED gi+gru (r18 version, proven) ============
__global__ __launch_bounds__(512, 1) void gru_kernel(
    const float* __restrict__ me_all, const unsigned int* __restrict__ wih4,
    const float* __restrict__ bih,
    const unsigned int* __restrict__ wgru4, const float* __restrict__ bhh,
    const float* __restrict__ fus_b, float* __restrict__ hB)
{
    __shared__ __align__(16) unsigned int wl[16 * 384 * 4];   // 96 KB
    __shared__ __align__(16) float me[2][DD];
    __shared__ unsigned int hpk[64];
    __shared__ float g_z[DD], g_inn[DD], g_hn[DD];
    int t = threadIdx.x;
    int b = blockIdx.x;
    int j = t & 127;
    int grp = t >> 7;

    {   // stage wih (96 KB) via global_load_lds
        const unsigned char* g = (const unsigned char*)wih4 + t * 16;
        unsigned char* l = (unsigned char*)wl + t * 16;
#pragma unroll
        for (int i = 0; i < 12; ++i) gld16(g + i * 8192, l + i * 8192);
    }
    uint4 w[16];
    const uint4* wg4 = (const uint4*)wgru4;
#pragma unroll
    for (int dd4 = 0; dd4 < 16; ++dd4) w[dd4] = wg4[dd4 * 512 + t];

    float bias_hh = (t < 384) ? bhh[t] : fus_b[j];
    float bias_ih = (t < 384) ? bih[t] : 0.0f;
    if (t < DD) me[0][t] = me_all[b * SS * DD + t];
    float hj = 0.0f;                 // grp0: exact f32 h[j]
    if (t < 64) hpk[t] = 0u;
    asm volatile("s_waitcnt vmcnt(0)" ::: "memory");
    __syncthreads();

    const uint4* wl4 = (const uint4*)wl;
    for (int s = 0; s < SS; ++s) {
        if (t < DD && s < 15) me[(s + 1) & 1][t] = me_all[(b * SS + s + 1) * DD + t];
        const float* mc = me[s & 1];
        float gi = bias_ih;
        if (grp < 3) {
#pragma unroll
            for (int dd4 = 0; dd4 < 16; ++dd4) {
                uint4 u = wl4[dd4 * 384 + t];
                float4 m0 = *(const float4*)&mc[8 * dd4];
                float4 m1 = *(const float4*)&mc[8 * dd4 + 4];
                gi += bflo(u.x) * m0.x + bfhi(u.x) * m0.y;
                gi += bflo(u.y) * m0.z + bfhi(u.y) * m0.w;
                gi += bflo(u.z) * m1.x + bfhi(u.z) * m1.y;
                gi += bflo(u.w) * m1.z + bfhi(u.w) * m1.w;
            }
        }
        float acc = bias_hh;
#pragma unroll
        for (int dd4 = 0; dd4 < 16; ++dd4) {
            uint4 hp = *(const uint4*)&hpk[dd4 * 4];
            uint4 u  = w[dd4];
            acc += bflo(u.x) * bflo(hp.x) + bfhi(u.x) * bfhi(hp.x);
            acc += bflo(u.y) * bflo(hp.y) + bfhi(u.y) * bfhi(hp.y);
            acc += bflo(u.z) * bflo(hp.z) + bfhi(u.z) * bfhi(hp.z);
            acc += bflo(u.w) * bflo(hp.w) + bfhi(u.w) * bfhi(hp.w);
        }
        if (grp == 3) {
            hB[(s * BB + b) * DD + j] = acc;          // h BEFORE update; fus_b included
        } else if (grp == 1) { g_z[j] = gi + acc; }
        else if (grp == 2)   { g_inn[j] = gi; g_hn[j] = acc; }
        __syncthreads();
        if (grp == 0) {
            float r = 1.0f / (1.0f + expf(-(gi + acc)));
            float z = 1.0f / (1.0f + expf(-g_z[j]));
            float n = tanhf(g_inn[j] + r * g_hn[j]);
            float hnew = (1.0f - z) * n + z * hj;
            hj = hnew;
            float hnb = __shfl_xor(hnew, 1);          // partner j^1 (same wave)
            if ((j & 1) == 0) {
                unsigned int pk;
                asm("v_cvt_pk_bf16_f32 %0, %1, %2" : "=v"(pk) : "v"(hnew), "v"(hnb));
                hpk[j >> 1] = pk;
            }
        }
        __syncthreads();
    }
}

// ============ kernel 4: MFMA TCN + fusion (v18: 4 tiles/block, 8 waves) ============
// Wave = (tile t = wv>>1 in 0..3, co-half nh = wv&1); per-wave code identical
// to v17. 16 KB super-chunks shared by all 4 tiles: barrier-instances per tile
// HALVED again, weight L2 traffic halved (1024 blocks). LDS = 107,520 B ->
// 1 block/CU, 8 waves (same resident-wave count as v17's 2 blocks x 4).
__global__ __launch_bounds__(512, 1) void tcn_kernel(
    const int* __restrict__ item_id, const float* __restrict__ emb,
    const int* __restrict__ maxlen,
    const unsigned short* __restrict__ wB2,
    const float* __restrict__ cb0, const float* __restrict__ cb1,
    const float* __restrict__ cb2,
    const float* __restrict__ hB, float* __restrict__ reps)
{
    __shared__ __align__(16) unsigned char lds_x[4][XT];    // 74752 B
    __shared__ __align__(16) unsigned char ring[2][16384];  // 32768 B -> 107520 total

    const int tid = threadIdx.x, bid = blockIdx.x;
    const int lane = tid & 63, wv = tid >> 6;
    const int l15 = lane & 15, q4 = lane >> 4;
    const int t = wv >> 1, nh = wv & 1;
    const int tile = bid * 4 + t;
    const int b = tile >> 4, s = tile & 15;
    const int ml = maxlen[s];

    const unsigned char* wgbase = (const unsigned char*)wB2;
    unsigned char* xb = lds_x[t];

    // stage super 0 -> ring[0]: 8 waves x 2 KB slices (uniform dst per wave)
    {
        const unsigned char* src = wgbase + wv * 2048 + lane * 16;
        gld16(src,        &ring[0][wv * 2048]);
        gld16(src + 1024, &ring[0][wv * 2048 + 1024]);
    }
    // hB fragments for the final writeout (ready: gru precedes tcn)
    float hb[4];
#pragma unroll
    for (int nt = 0; nt < 4; ++nt)
        hb[nt] = hB[(s * BB + b) * DD + nh * 64 + nt * 16 + l15];

    // transient seqs in ring[1] (free until super 1 is staged at sc=0)
    int* seqs2 = (int*)&ring[1][0];
    if (tid < 4 * TT) {
        int tt = tid / TT, p = tid - tt * TT;
        int tl = bid * 4 + tt;
        int v;
        if (p == 0) v = BOS_ID;
        else { int it = item_id[tl * II + p - 1]; v = it > 0 ? it : 0; }
        if (p > maxlen[tl & 15]) v = 0;
        seqs2[tt * TT + p] = v;
    }
    // zero guard rows 0..7 of all 4 tiles (2048 B each = 8192 B total)
    {
        float4 z = {0.f, 0.f, 0.f, 0.f};
        *(float4*)(lds_x[tid >> 7] + (tid & 127) * 16) = z;
    }
    __syncthreads();

    // gather embeddings -> rows 8..72 of own tile (bf16 pairs, swizzled);
    // the two nh-waves of a tile split rows by parity.
    for (int p = nh; p < TT; p += 2) {
        const float* er = emb + (long)seqs2[t * TT + p] * DD + lane * 2;
        float f0 = er[0], f1 = er[1];
        unsigned int pk = ((unsigned int)f2bf(f1) << 16) | (unsigned int)f2bf(f0);
        *(unsigned int*)(xb + (8 + p) * XROW + ((lane * 4) ^ ((p & 7) << 4))) = pk;
    }

    f32x4 acc[5][4];

#pragma unroll 1
    for (int sc = 0; sc < 20; ++sc) {
        if (sc == 18 || (sc < 18 && sc % 6 == 0)) {   // zero acc at layer/fusion start
#pragma unroll
            for (int mt = 0; mt < 5; ++mt)
#pragma unroll
                for (int nt = 0; nt < 4; ++nt)
#pragma unroll
                    for (int r = 0; r < 4; ++r) acc[mt][nt][r] = 0.0f;
        }
        // explicit drain of this wave's staging loads, then the barrier
        // publishes all 8 waves' slices of slot sc&1, guards (sc+1)&1 reuse,
        // and publishes the previous layer epilogue's x-writes.
        asm volatile("s_waitcnt vmcnt(0)" ::: "memory");
        __syncthreads();

        if (sc <= 18) {   // stage super sc+1 (2 KB slice per wave, uniform dst)
            const unsigned char* src =
                wgbase + (size_t)(sc + 1) * 16384 + wv * 2048 + lane * 16;
            unsigned char* dst = &ring[(sc + 1) & 1][wv * 2048];
            gld16(src,        dst);
            gld16(src + 1024, dst + 1024);
        }

#pragma unroll
        for (int half = 0; half < 2; ++half) {
            int cid = 2 * sc + half;
            int L = 0, cq, off;
            if (cid < 36) { L = cid / 12; int kq = cid - L * 12; int k = kq >> 2; cq = kq & 3; off = (2 - k) << L; }
            else { cq = cid - 36; off = 0; }
            const unsigned char* sb = &ring[sc & 1][half * 8192 + nh * 4096];
            const int xmask = ((l15 - off) & 7) << 4;      // uniform across mt
            const int colx  = (cq * 64 + q4 * 16) ^ xmask;
            short8 bfr[4], af[5];
#pragma unroll
            for (int nt = 0; nt < 4; ++nt)
                bfr[nt] = *(const short8*)(sb + q4 * 1024 + (nt * 16 + l15) * 16);
#pragma unroll
            for (int mt = 0; mt < 5; ++mt) {
                int rowA = 8 + mt * 16 + l15 - off;
                af[mt] = *(const short8*)(xb + rowA * XROW + colx);
            }
#pragma unroll
            for (int nt = 0; nt < 4; ++nt)
#pragma unroll
                for (int mt = 0; mt < 5; ++mt)
                    acc[mt][nt] = __builtin_amdgcn_mfma_f32_16x16x32_bf16(
                        af[mt], bfr[nt], acc[mt][nt], 0, 0, 0);
        }

        if (sc < 18 && sc % 6 == 5) {   // layer epilogue: relu(acc+bias) -> x
            int L = sc / 6;
            const float* cb = (L == 0) ? cb0 : ((L == 1) ? cb1 : cb2);
            __syncthreads();          // all reads of current x done
#pragma unroll
            for (int nt = 0; nt < 4; ++nt) {
                float bia = cb[nh * 64 + nt * 16 + l15];
                int cbyte = nh * 128 + nt * 32 + l15 * 2;
#pragma unroll
                for (int mt = 0; mt < 5; ++mt)
#pragma unroll
                    for (int r = 0; r < 4; ++r) {
                        int p = mt * 16 + q4 * 4 + r;
                        if (p < TT) {
                            int row = 8 + p;
                            float v = acc[mt][nt][r] + bia;
                            *(unsigned short*)(xb + row * XROW +
                                               (cbyte ^ ((row & 7) << 4))) =
                                f2bf(v > 0.f ? v : 0.f);
                        }
                    }
            }
            // no trailing barrier: next super's top-of-loop barrier covers it.
        }
    }

    // fusion writeout: reps[p][co] = (p<=ml) ? acc + hb : 0   (coalesced)
    long ob = (long)tile * (TT * DD);
#pragma unroll
    for (int mt = 0; mt < 5; ++mt)
#pragma unroll
        for (int nt = 0; nt < 4; ++nt)
#pragma unroll
            for (int r = 0; r < 4; ++r) {
                int p = mt * 16 + q4 * 4 + r;
                if (p < TT) {
                    float v = (p <= ml) ? (acc[mt][nt][r] + hb[nt]) : 0.0f;
                    reps[ob + p * DD + nh * 64 + nt * 16 + l15] = v;
                }
            }
}

extern "C" void kernel_launch(void* const* d_in, const int* in_sizes, int n_in,
                              void* d_out, int out_size, void* d_ws, size_t ws_size,
                              hipStream_t stream) {
    const int*   item_id   = (const int*)  d_in[0];
    const int*   eval_from = (const int*)  d_in[1];
    const int*   u_type    = (const int*)  d_in[2];
    const float* emb       = (const float*)d_in[3];
    const float* conv_w0   = (const float*)d_in[4];
    const float* conv_b0   = (const float*)d_in[5];
    const float* conv_w1   = (const float*)d_in[6];
    const float* conv_b1   = (const float*)d_in[7];
    const float* conv_w2   = (const float*)d_in[8];
    const float* conv_b2   = (const float*)d_in[9];
    const float* gru_wih   = (const float*)d_in[10];
    const float* gru_whh   = (const float*)d_in[11];
    const float* gru_bih   = (const float*)d_in[12];
    const float* gru_bhh   = (const float*)d_in[13];
    const float* fus_w     = (const float*)d_in[14];
    const float* fus_b     = (const float*)d_in[15];

    char* ws = (char*)d_ws;
    int*            lengths  = (int*)           (ws + OFF_LEN);
    int*            maxlen   = (int*)           (ws + OFF_ML);
    float*          mean_emb = (float*)         (ws + OFF_ME);
    float*          hB       = (float*)         (ws + OFF_HB);
    unsigned short* wB2      = (unsigned short*)(ws + OFF_WB2);
    unsigned int*   wih4     = (unsigned int*)  (ws + OFF_WIHP);
    unsigned int*   wgru4    = (unsigned int*)  (ws + OFF_WGRU);

    float* out  = (float*)d_out;
    float* reps = out;
    float* mout = out + OUT_MASK;
    float* uout = out + OUT_UTYPE;

    prep_kernel<<<880, 256, 0, stream>>>(conv_w0, conv_w1, conv_w2, fus_w,
                                         gru_wih, gru_whh, item_id, u_type,
                                         wB2, wih4, wgru4, lengths, maxlen, uout);
    mean_kernel<<<BB * SS, 256, 0, stream>>>(item_id, eval_from, emb, lengths, maxlen,
                                             mean_emb, mout);
    gru_kernel<<<BB, 512, 0, stream>>>(mean_emb, wih4, gru_bih,
                                       wgru4, gru_bhh, fus_b, hB);
    tcn_kernel<<<BB * SS / 4, 512, 0, stream>>>(item_id, emb, maxlen, wB2,
                                                conv_b0, conv_b1, conv_b2, hB, reps);
}

// Round 24
// 234.006 us; speedup vs baseline: 1.1010x; 1.1010x over previous
//
#include <hip/hip_runtime.h>

#define BB 256
#define SS 16
#define II 64
#define DD 128
#define TT 65            // I + 1 (BOS prepended)
#define BOS_ID 100000
#define XROW 256         // x row stride: 128 bf16, XOR-16B swizzled (byte ^= (row&7)<<4)
#define XROWS 73         // 8 zero guard rows + 65 positions
#define XT (XROWS*XROW)  // 18688 B per tile

// ---------------- ws layout (bytes) ----------------
#define OFF_LEN  0                        // int lengths[B][S]            16384
#define OFF_ML   16384                    // int maxlen[S]                64
#define OFF_ME   32768                    // float mean_emb[B][S][D]      2 MB
#define OFF_HB   (32768 + 2097152)        // float hB[S][B][D]            2 MB
#define OFF_WB2  (OFF_HB + 2097152)       // bf16 wB2[80 half-chunks][2048]  327680
#define OFF_WIHP (OFF_WB2 + 327680)       // u32 wih4[16][384][4]         98304
#define OFF_WGRU (OFF_WIHP + 98304)       // u32 wgru4[16][512][4]        131072

// ---------------- out layout (float elements) ----------------
#define OUT_MASK  (BB*SS*TT*DD)          // 34,078,720
#define OUT_UTYPE (OUT_MASK + BB*SS*TT)

typedef __attribute__((ext_vector_type(8))) short short8;
typedef __attribute__((ext_vector_type(4))) float f32x4;

__device__ __forceinline__ unsigned short f2bf(float f) {
    unsigned int u = __builtin_bit_cast(unsigned int, f);
    return (unsigned short)((u + 0x7fffu + ((u >> 16) & 1u)) >> 16);  // RNE
}
__device__ __forceinline__ float bflo(unsigned int u) {
    return __builtin_bit_cast(float, u << 16);
}
__device__ __forceinline__ float bfhi(unsigned int u) {
    return __builtin_bit_cast(float, u & 0xffff0000u);
}
__device__ __forceinline__ void gld16(const void* g, void* l) {
    __builtin_amdgcn_global_load_lds(
        (const __attribute__((address_space(1))) void*)g,
        (__attribute__((address_space(3))) void*)l, 16, 0, 0);
}

// ============ kernel 0: weight prep + len (merged; len = blocks 864..879) ============
__global__ __launch_bounds__(256) void prep_kernel(
    const float* __restrict__ w0, const float* __restrict__ w1,
    const float* __restrict__ w2, const float* __restrict__ fus_w,
    const float* __restrict__ wih, const float* __restrict__ whh,
    const int* __restrict__ item_id, const int* __restrict__ u_type,
    unsigned short* __restrict__ wB2,
    unsigned int* __restrict__ wih4, unsigned int* __restrict__ wgru4,
    int* __restrict__ lengths, int* __restrict__ maxlen,
    float* __restrict__ u_out)
{
    if (blockIdx.x >= 864) {            // ---- len work ----
        int s = blockIdx.x - 864;
        int b = threadIdx.x;
        const int* row = item_id + (b * SS + s) * II;
        int cnt = 0;
        for (int i = 0; i < II; ++i) cnt += (row[i] > 0);
        lengths[b * SS + s] = cnt;
        __shared__ int red[256];
        red[b] = cnt;
        __syncthreads();
        for (int off = 128; off > 0; off >>= 1) {
            if (b < off) red[b] = max(red[b], red[b + off]);
            __syncthreads();
        }
        if (b == 0) maxlen[s] = red[0];
        if (s == 0) u_out[b] = (float)u_type[b];
        return;
    }
    int idx = blockIdx.x * 256 + threadIdx.x;
    if (idx < 163840) {
        int cid2  = idx >> 11;           // 0..79
        int inner = idx & 2047;
        int g = inner >> 9;
        int c = (inner >> 3) & 63;
        int e = inner & 7;
        int nh   = cid2 & 1;
        int rest = cid2 >> 1;            // 0..39
        int cq   = rest & 3;
        int m    = rest >> 2;            // 0..8 conv, 9 fusion
        int ci = cq * 32 + g * 8 + e;
        int co = nh * 64 + c;
        float v;
        if (m < 9) {
            int L = m / 3, k = m % 3;
            const float* w = (L == 0) ? w0 : ((L == 1) ? w1 : w2);
            v = w[(co * 128 + ci) * 3 + k];
            if (k == 2 && ci == co) v += 1.0f;   // fold residual into GEMM
        } else {
            v = fus_w[co * 256 + ci];    // tc half of fus_w
        }
        wB2[idx] = f2bf(v);
    } else if (idx < 163840 + 24576) {
        int f   = idx - 163840;          // [dd4][r][c]: 16 x 384 x 4
        int dd4 = f / 1536;
        int rem = f - dd4 * 1536;
        int r   = rem >> 2;
        int c   = rem & 3;
        int d0  = 8 * dd4 + 2 * c;
        unsigned int lo = f2bf(wih[r * 128 + d0]);
        unsigned int hi = f2bf(wih[r * 128 + d0 + 1]);
        wih4[f] = (hi << 16) | lo;
    } else if (idx < 163840 + 24576 + 32768) {
        int f   = idx - 163840 - 24576;  // [dd4][r][c]: 16 x 512 x 4
        int dd4 = f >> 11;
        int rem = f & 2047;
        int r   = rem >> 2;
        int c   = rem & 3;
        int d0  = 8 * dd4 + 2 * c;
        float v0, v1;
        if (r < 384) { v0 = whh[r * 128 + d0]; v1 = whh[r * 128 + d0 + 1]; }
        else { const float* fw = fus_w + (r - 384) * 256 + 128;
               v0 = fw[d0]; v1 = fw[d0 + 1]; }
        wgru4[f] = ((unsigned int)f2bf(v1) << 16) | (unsigned int)f2bf(v0);
    }
}

// ============ kernel 2: masks + mean_emb v2 (256 thr, row-parity split) ============
__global__ __launch_bounds__(256) void mean_kernel(
    const int* __restrict__ item_id, const int* __restrict__ eval_from,
    const float* __restrict__ emb,
    const int* __restrict__ lengths, const int* __restrict__ maxlen,
    float* __restrict__ mean_emb, float* __restrict__ mask_out)
{
    int bid = blockIdx.x;
    int b = bid >> 4, s = bid & 15;
    int tid = threadIdx.x;
    int d = tid & 127, tg = tid >> 7;
    __shared__ int seqs[TT];
    __shared__ int msk[TT];
    __shared__ float part[DD];
    int ml  = maxlen[s];
    int len = lengths[bid];
    int ef  = eval_from[b];
    if (tid < TT) {
        int v;
        if (tid == 0) v = BOS_ID;
        else { int it = item_id[bid * II + tid - 1]; v = it > 0 ? it : 0; }
        if (tid > ml) v = 0;
        int m = (v != 0) && !(tid == len && len > 0);
        seqs[tid] = v;
        msk[tid]  = m;
        mask_out[bid * TT + tid] = (m && (s >= ef)) ? 1.0f : 0.0f;
    }
    __syncthreads();
    int cnt = 0;
    for (int p = 0; p < TT; ++p) cnt += msk[p];
    float acc = 0.0f;
    for (int p = tg; p < TT; p += 2) {
        if (msk[p]) acc += emb[(long)seqs[p] * DD + d];
    }
    if (tg == 1) part[d] = acc;
    __syncthreads();
    if (tg == 0)
        mean_emb[bid * DD + d] = (acc + part[d]) / (float)max(cnt, 1);
}

// ============ kernel 3: FUSED gi+gru (r18 version, proven) ============
__global__ __launch_bounds__(512, 1) void gru_kernel(
    const float* __restrict__ me_all, const unsigned int* __restrict__ wih4,
    const float* __restrict__ bih,
    const unsigned int* __restrict__ wgru4, const float* __restrict__ bhh,
    const float* __restrict__ fus_b, float* __restrict__ hB)
{
    __shared__ __align__(16) unsigned int wl[16 * 384 * 4];   // 96 KB
    __shared__ __align__(16) float me[2][DD];
    __shared__ unsigned int hpk[64];
    __shared__ float g_z[DD], g_inn[DD], g_hn[DD];
    int t = threadIdx.x;
    int b = blockIdx.x;
    int j = t & 127;
    int grp = t >> 7;

    {   // stage wih (96 KB) via global_load_lds
        const unsigned char* g = (const unsigned char*)wih4 + t * 16;
        unsigned char* l = (unsigned char*)wl + t * 16;
#pragma unroll
        for (int i = 0; i < 12; ++i) gld16(g + i * 8192, l + i * 8192);
    }
    uint4 w[16];
    const uint4* wg4 = (const uint4*)wgru4;
#pragma unroll
    for (int dd4 = 0; dd4 < 16; ++dd4) w[dd4] = wg4[dd4 * 512 + t];

    float bias_hh = (t < 384) ? bhh[t] : fus_b[j];
    float bias_ih = (t < 384) ? bih[t] : 0.0f;
    if (t < DD) me[0][t] = me_all[b * SS * DD + t];
    float hj = 0.0f;                 // grp0: exact f32 h[j]
    if (t < 64) hpk[t] = 0u;
    asm volatile("s_waitcnt vmcnt(0)" ::: "memory");
    __syncthreads();

    const uint4* wl4 = (const uint4*)wl;
    for (int s = 0; s < SS; ++s) {
        if (t < DD && s < 15) me[(s + 1) & 1][t] = me_all[(b * SS + s + 1) * DD + t];
        const float* mc = me[s & 1];
        float gi = bias_ih;
        if (grp < 3) {
#pragma unroll
            for (int dd4 = 0; dd4 < 16; ++dd4) {
                uint4 u = wl4[dd4 * 384 + t];
                float4 m0 = *(const float4*)&mc[8 * dd4];
                float4 m1 = *(const float4*)&mc[8 * dd4 + 4];
                gi += bflo(u.x) * m0.x + bfhi(u.x) * m0.y;
                gi += bflo(u.y) * m0.z + bfhi(u.y) * m0.w;
                gi += bflo(u.z) * m1.x + bfhi(u.z) * m1.y;
                gi += bflo(u.w) * m1.z + bfhi(u.w) * m1.w;
            }
        }
        float acc = bias_hh;
#pragma unroll
        for (int dd4 = 0; dd4 < 16; ++dd4) {
            uint4 hp = *(const uint4*)&hpk[dd4 * 4];
            uint4 u  = w[dd4];
            acc += bflo(u.x) * bflo(hp.x) + bfhi(u.x) * bfhi(hp.x);
            acc += bflo(u.y) * bflo(hp.y) + bfhi(u.y) * bfhi(hp.y);
            acc += bflo(u.z) * bflo(hp.z) + bfhi(u.z) * bfhi(hp.z);
            acc += bflo(u.w) * bflo(hp.w) + bfhi(u.w) * bfhi(hp.w);
        }
        if (grp == 3) {
            hB[(s * BB + b) * DD + j] = acc;          // h BEFORE update; fus_b included
        } else if (grp == 1) { g_z[j] = gi + acc; }
        else if (grp == 2)   { g_inn[j] = gi; g_hn[j] = acc; }
        __syncthreads();
        if (grp == 0) {
            float r = 1.0f / (1.0f + expf(-(gi + acc)));
            float z = 1.0f / (1.0f + expf(-g_z[j]));
            float n = tanhf(g_inn[j] + r * g_hn[j]);
            float hnew = (1.0f - z) * n + z * hj;
            hj = hnew;
            float hnb = __shfl_xor(hnew, 1);          // partner j^1 (same wave)
            if ((j & 1) == 0) {
                unsigned int pk;
                asm("v_cvt_pk_bf16_f32 %0, %1, %2" : "=v"(pk) : "v"(hnew), "v"(hnb));
                hpk[j >> 1] = pk;
            }
        }
        __syncthreads();
    }
}

// ============ kernel 4: MFMA TCN + fusion (v17: proven best, 157 µs) ============
__global__ __launch_bounds__(256, 2) void tcn_kernel(
    const int* __restrict__ item_id, const float* __restrict__ emb,
    const int* __restrict__ maxlen,
    const unsigned short* __restrict__ wB2,
    const float* __restrict__ cb0, const float* __restrict__ cb1,
    const float* __restrict__ cb2,
    const float* __restrict__ hB, float* __restrict__ reps)
{
    __shared__ __align__(16) unsigned char lds_x[2][XT];    // 37376 B
    __shared__ __align__(16) unsigned char ring[2][16384];  // 32768 B -> 70144 total

    const int tid = threadIdx.x, bid = blockIdx.x;
    const int lane = tid & 63, wv = tid >> 6;
    const int l15 = lane & 15, q4 = lane >> 4;
    const int t = wv >> 1, nh = wv & 1;
    const int tile = bid * 2 + t;
    const int b = tile >> 4, s = tile & 15;
    const int ml = maxlen[s];

    const unsigned char* wgbase = (const unsigned char*)wB2;
    unsigned char* xb = lds_x[t];

    // stage super 0 -> ring[0] (4 x 4 KB slices per wave, uniform dst)
    {
        const unsigned char* src = wgbase + wv * 1024 + lane * 16;
        gld16(src,         &ring[0][wv * 1024]);
        gld16(src + 4096,  &ring[0][4096 + wv * 1024]);
        gld16(src + 8192,  &ring[0][8192 + wv * 1024]);
        gld16(src + 12288, &ring[0][12288 + wv * 1024]);
    }
    // hB fragments for the final writeout — ready now (gru precedes tcn);
    // hoisted here so their latency hides under the whole pipeline.
    float hb[4];
#pragma unroll
    for (int nt = 0; nt < 4; ++nt)
        hb[nt] = hB[(s * BB + b) * DD + nh * 64 + nt * 16 + l15];

    // transient seqs in ring[1] (free until super 1 is staged at sc=0)
    int* seqs2 = (int*)&ring[1][0];
    if (tid < 2 * TT) {
        int tt = tid / TT, p = tid - tt * TT;
        int tl = bid * 2 + tt;
        int v;
        if (p == 0) v = BOS_ID;
        else { int it = item_id[tl * II + p - 1]; v = it > 0 ? it : 0; }
        if (p > maxlen[tl & 15]) v = 0;
        seqs2[tt * TT + p] = v;
    }
    // zero guard rows 0..7 of both tiles (2048 B each)
    {
        float4 z = {0.f, 0.f, 0.f, 0.f};
        if (tid < 128) *(float4*)(lds_x[0] + tid * 16) = z;
        else           *(float4*)(lds_x[1] + (tid - 128) * 16) = z;
    }
    __syncthreads();

    // gather embeddings -> rows 8..72 of own tile (bf16 pairs, swizzled);
    // the two nh-waves of a tile split rows by parity.
    for (int p = nh; p < TT; p += 2) {
        const float* er = emb + (long)seqs2[t * TT + p] * DD + lane * 2;
        float f0 = er[0], f1 = er[1];
        unsigned int pk = ((unsigned int)f2bf(f1) << 16) | (unsigned int)f2bf(f0);
        *(unsigned int*)(xb + (8 + p) * XROW + ((lane * 4) ^ ((p & 7) << 4))) = pk;
    }

    f32x4 acc[5][4];

#pragma unroll 1
    for (int sc = 0; sc < 20; ++sc) {
        if (sc == 18 || (sc < 18 && sc % 6 == 0)) {   // zero acc at layer/fusion start
#pragma unroll
            for (int mt = 0; mt < 5; ++mt)
#pragma unroll
                for (int nt = 0; nt < 4; ++nt)
#pragma unroll
                    for (int r = 0; r < 4; ++r) acc[mt][nt][r] = 0.0f;
        }
        // explicit drain of this wave's staging loads, then the barrier
        // publishes all 4 waves' slices of slot sc&1, guards (sc+1)&1 reuse,
        // AND (via its implicit lgkmcnt drain) publishes the previous layer
        // epilogue's x-writes before this super's af reads.
        asm volatile("s_waitcnt vmcnt(0)" ::: "memory");
        __syncthreads();

        if (sc <= 18) {   // stage super sc+1 (4 slices, uniform dst per wave)
            const unsigned char* src =
                wgbase + (size_t)(sc + 1) * 16384 + wv * 1024 + lane * 16;
            unsigned char* dst = &ring[(sc + 1) & 1][0];
            gld16(src,         dst + wv * 1024);
            gld16(src + 4096,  dst + 4096 + wv * 1024);
            gld16(src + 8192,  dst + 8192 + wv * 1024);
            gld16(src + 12288, dst + 12288 + wv * 1024);
        }

#pragma unroll
        for (int half = 0; half < 2; ++half) {
            int cid = 2 * sc + half;
            int L = 0, cq, off;
            if (cid < 36) { L = cid / 12; int kq = cid - L * 12; int k = kq >> 2; cq = kq & 3; off = (2 - k) << L; }
            else { cq = cid - 36; off = 0; }
            const unsigned char* sb = &ring[sc & 1][half * 8192 + nh * 4096];
            const int xmask = ((l15 - off) & 7) << 4;      // uniform across mt
            const int colx  = (cq * 64 + q4 * 16) ^ xmask;
            short8 bfr[4], af[5];
#pragma unroll
            for (int nt = 0; nt < 4; ++nt)
                bfr[nt] = *(const short8*)(sb + q4 * 1024 + (nt * 16 + l15) * 16);
#pragma unroll
            for (int mt = 0; mt < 5; ++mt) {
                int rowA = 8 + mt * 16 + l15 - off;
                af[mt] = *(const short8*)(xb + rowA * XROW + colx);
            }
#pragma unroll
            for (int nt = 0; nt < 4; ++nt)
#pragma unroll
                for (int mt = 0; mt < 5; ++mt)
                    acc[mt][nt] = __builtin_amdgcn_mfma_f32_16x16x32_bf16(
                        af[mt], bfr[nt], acc[mt][nt], 0, 0, 0);
        }

        if (sc < 18 && sc % 6 == 5) {   // layer epilogue: relu(acc+bias) -> x
            int L = sc / 6;
            const float* cb = (L == 0) ? cb0 : ((L == 1) ? cb1 : cb2);
            __syncthreads();          // all reads of current x done (both tile-waves)
#pragma unroll
            for (int nt = 0; nt < 4; ++nt) {
                float bia = cb[nh * 64 + nt * 16 + l15];
                int cbyte = nh * 128 + nt * 32 + l15 * 2;
#pragma unroll
                for (int mt = 0; mt < 5; ++mt)
#pragma unroll
                    for (int r = 0; r < 4; ++r) {
                        int p = mt * 16 + q4 * 4 + r;
                        if (p < TT) {
                            int row = 8 + p;
                            float v = acc[mt][nt][r] + bia;
                            *(unsigned short*)(xb + row * XROW +
                                               (cbyte ^ ((row & 7) << 4))) =
                                f2bf(v > 0.f ? v : 0.f);
                        }
                    }
            }
            // no trailing barrier: next super's top-of-loop barrier drains
            // lgkmcnt (writes land) before any wave's af reads of the new layer.
        }
    }

    // fusion writeout: reps[p][co] = (p<=ml) ? acc + hb : 0   (coalesced)
    long ob = (long)tile * (TT * DD);
#pragma unroll
    for (int mt = 0; mt < 5; ++mt)
#pragma unroll
        for (int nt = 0; nt < 4; ++nt)
#pragma unroll
            for (int r = 0; r < 4; ++r) {
                int p = mt * 16 + q4 * 4 + r;
                if (p < TT) {
                    float v = (p <= ml) ? (acc[mt][nt][r] + hb[nt]) : 0.0f;
                    reps[ob + p * DD + nh * 64 + nt * 16 + l15] = v;
                }
            }
}

extern "C" void kernel_launch(void* const* d_in, const int* in_sizes, int n_in,
                              void* d_out, int out_size, void* d_ws, size_t ws_size,
                              hipStream_t stream) {
    const int*   item_id   = (const int*)  d_in[0];
    const int*   eval_from = (const int*)  d_in[1];
    const int*   u_type    = (const int*)  d_in[2];
    const float* emb       = (const float*)d_in[3];
    const float* conv_w0   = (const float*)d_in[4];
    const float* conv_b0   = (const float*)d_in[5];
    const float* conv_w1   = (const float*)d_in[6];
    const float* conv_b1   = (const float*)d_in[7];
    const float* conv_w2   = (const float*)d_in[8];
    const float* conv_b2   = (const float*)d_in[9];
    const float* gru_wih   = (const float*)d_in[10];
    const float* gru_whh   = (const float*)d_in[11];
    const float* gru_bih   = (const float*)d_in[12];
    const float* gru_bhh   = (const float*)d_in[13];
    const float* fus_w     = (const float*)d_in[14];
    const float* fus_b     = (const float*)d_in[15];

    char* ws = (char*)d_ws;
    int*            lengths  = (int*)           (ws + OFF_LEN);
    int*            maxlen   = (int*)           (ws + OFF_ML);
    float*          mean_emb = (float*)         (ws + OFF_ME);
    float*          hB       = (float*)         (ws + OFF_HB);
    unsigned short* wB2      = (unsigned short*)(ws + OFF_WB2);
    unsigned int*   wih4     = (unsigned int*)  (ws + OFF_WIHP);
    unsigned int*   wgru4    = (unsigned int*)  (ws + OFF_WGRU);

    float* out  = (float*)d_out;
    float* reps = out;
    float* mout = out + OUT_MASK;
    float* uout = out + OUT_UTYPE;

    prep_kernel<<<880, 256, 0, stream>>>(conv_w0, conv_w1, conv_w2, fus_w,
                                         gru_wih, gru_whh, item_id, u_type,
                                         wB2, wih4, wgru4, lengths, maxlen, uout);
    mean_kernel<<<BB * SS, 256, 0, stream>>>(item_id, eval_from, emb, lengths, maxlen,
                                             mean_emb, mout);
    gru_kernel<<<BB, 512, 0, stream>>>(mean_emb, wih4, gru_bih,
                                       wgru4, gru_bhh, fus_b, hB);
    tcn_kernel<<<BB * SS / 2, 256, 0, stream>>>(item_id, emb, maxlen, wB2,
                                                conv_b0, conv_b1, conv_b2, hB, reps);
}